// Round 8
// baseline (203.603 us; speedup 1.0000x reference)
//
#include <hip/hip_runtime.h>
#include <hip/hip_bf16.h>

#define BS    128
#define NCIN  64
#define NCOUT 64
#define LLEN  8192
#define NK    3
#define NR    8
#define NEMB  256
#define NHID  256
#define WPS   (NCOUT * NCIN * NK)   // 12288 weights per sample
#define NT    256                   // l-positions per conv block

typedef __attribute__((ext_vector_type(4)))  float  f32x4;
typedef __attribute__((ext_vector_type(16))) float  f32x16;
typedef __attribute__((ext_vector_type(8)))  __bf16 bf16x8;

// Static device scratch (fully rewritten every call).
__device__ float  g_A[BS * 512];    // A factors [b][ci*8+r]
__device__ float  g_B[BS * 1536];   // B factors [b][r*192+co*3+k]
__device__ __bf16 g_Wb[BS * WPS];   // W_eff bf16 [b][k*4096+co*64+ci]

// ---------------------------------------------------------------------------
// Kernel 1: MLP branches. 256 blocks: block = (branch, sample).
// ---------------------------------------------------------------------------
__global__ __launch_bounds__(256) void mlp_kernel(
    const float* __restrict__ a_emb, const float* __restrict__ b_emb,
    const float* __restrict__ A_w1, const float* __restrict__ A_b1,
    const float* __restrict__ A_g,  const float* __restrict__ A_beta,
    const float* __restrict__ A_w2, const float* __restrict__ A_b2,
    const float* __restrict__ B_w1, const float* __restrict__ B_b1,
    const float* __restrict__ B_g,  const float* __restrict__ B_beta,
    const float* __restrict__ B_w2, const float* __restrict__ B_b2)
{
    __shared__ __align__(16) float emb_s[NEMB];
    __shared__ __align__(16) float h_s[NHID];

    const int t      = threadIdx.x;
    const int branch = blockIdx.x >> 7;
    const int b      = blockIdx.x & 127;

    const float* emb  = (branch ? b_emb : a_emb) + (size_t)b * NEMB;
    const float* w1   = branch ? B_w1 : A_w1;
    const float* b1   = branch ? B_b1 : A_b1;
    const float* gg   = branch ? B_g  : A_g;
    const float* bt   = branch ? B_beta : A_beta;
    const float* w2   = branch ? B_w2 : A_w2;
    const float* b2   = branch ? B_b2 : A_b2;
    float* outp       = (branch ? g_B : g_A) + (size_t)b * (branch ? 1536 : 512);
    const int nloops  = branch ? 6 : 2;

    emb_s[t] = emb[t];
    __syncthreads();

    // hidden: Linear + BN(eval, mean=0 var=1) + exact GELU
    {
        float acc = b1[t];
        const f32x4* wr = (const f32x4*)(w1 + (size_t)t * NEMB);
        const f32x4* es = (const f32x4*)emb_s;
        for (int e = 0; e < NEMB / 4; ++e) {
            f32x4 w = wr[e], a = es[e];
            acc += w[0]*a[0] + w[1]*a[1] + w[2]*a[2] + w[3]*a[3];
        }
        float h = acc * (gg[t] * (1.0f / sqrtf(1.0f + 1e-5f))) + bt[t];
        h = 0.5f * h * (1.0f + erff(h * 0.70710678118654752f));
        h_s[t] = h;
    }
    __syncthreads();

    // outputs
    for (int oo = 0; oo < nloops; ++oo) {
        const int o = oo * 256 + t;
        float acc = b2[o];
        const f32x4* wr = (const f32x4*)(w2 + (size_t)o * NHID);
        const f32x4* hs = (const f32x4*)h_s;
        for (int e = 0; e < NHID / 4; ++e) {
            f32x4 w = wr[e], h = hs[e];
            acc += w[0]*h[0] + w[1]*h[1] + w[2]*h[2] + w[3]*h[3];
        }
        outp[o] = acc;
    }
}

// ---------------------------------------------------------------------------
// Kernel 2: assemble W_eff = base_w + A·B  (bf16, [b][k*4096+co*64+ci]).
// ---------------------------------------------------------------------------
__global__ __launch_bounds__(256) void assemble_kernel(const float* __restrict__ base_w)
{
    const int b  = blockIdx.x >> 2;
    const int q  = blockIdx.x & 3;
    const int t  = threadIdx.x;
    const int ci = t & 63;

    float Ar[NR];
    const f32x4* Ap = (const f32x4*)(g_A + (size_t)b * 512 + ci * NR);
    f32x4 a0 = Ap[0], a1 = Ap[1];
    Ar[0]=a0[0]; Ar[1]=a0[1]; Ar[2]=a0[2]; Ar[3]=a0[3];
    Ar[4]=a1[0]; Ar[5]=a1[1]; Ar[6]=a1[2]; Ar[7]=a1[3];

    const float* Bp = g_B + (size_t)b * 1536;
    for (int i = 0; i < 12; ++i) {
        const int w  = q * 3072 + i * 256 + t;
        const int k  = w >> 12;
        const int co = (w >> 6) & 63;
        float v = base_w[(size_t)(co * 64 + ci) * 3 + k];
        #pragma unroll
        for (int r = 0; r < NR; ++r) v += Ar[r] * Bp[r * 192 + co * 3 + k];
        g_Wb[(size_t)b * WPS + w] = (__bf16)v;
    }
}

// ---------------------------------------------------------------------------
// Kernel 3: per-sample conv as MFMA GEMM, 32x32x16 shape. Block = (b, 256-l tile).
// LDS: X tile transposed [lp][ci] bf16, XOR-swizzled blk = (ci>>3)^(lp&7)^((lp>>3)&7).
// Per wave: 32 co (wco half) x 128 l (wl half); 48 MFMA, 48 ds_read_b128.
// LDS reused as f32 [32][258] for the coalesced-store epilogue (two co passes).
// ---------------------------------------------------------------------------
__global__ __launch_bounds__(256) void conv_kernel(
    const float* __restrict__ X, const float* __restrict__ base_b,
    float* __restrict__ out)
{
    __shared__ __align__(16) unsigned char smem[33024];  // = 258*64*2 = 32*258*4
    __bf16* xt = (__bf16*)smem;
    float*  ot = (float*)smem;

    const int t     = threadIdx.x;
    const int b     = blockIdx.x >> 5;    // 32 tiles per sample
    const int tile  = blockIdx.x & 31;
    const int l0    = tile * NT;
    const int lane  = t & 63;
    const int wave  = t >> 6;
    const int l31   = lane & 31;
    const int khalf = lane >> 5;          // which 8-k (=ci) slice within K=16
    const int wco   = wave >> 1;          // which 32 co
    const int wl    = wave & 1;           // which 128 l

    // ---- stage X tile: 8ci x 8l micro-tile per thread (conflict-free b128 writes) ----
    {
        const int lb = t & 31;           // l-block of 8
        const int cb = t >> 5;           // ci-block of 8
        f32x4 v[8][2];
        const float* xb = X + (size_t)b * NCIN * LLEN + l0 + lb * 8;
        #pragma unroll
        for (int c = 0; c < 8; ++c) {
            const float* xr = xb + (size_t)(cb * 8 + c) * LLEN;
            v[c][0] = *(const f32x4*)(xr);
            v[c][1] = *(const f32x4*)(xr + 4);
        }
        #pragma unroll
        for (int j = 0; j < 8; ++j) {
            const int lp = lb * 8 + j + 1;
            bf16x8 w;
            #pragma unroll
            for (int c = 0; c < 8; ++c) w[c] = (__bf16)v[c][j >> 2][j & 3];
            const int blk = cb ^ (lp & 7) ^ ((lp >> 3) & 7);
            *(bf16x8*)(xt + lp * 64 + blk * 8) = w;
        }
    }
    if (t < 128) {  // halo columns (pad = 1)
        const int ci    = t & 63;
        const int right = t >> 6;
        const int gl    = right ? (l0 + NT) : (l0 - 1);
        const int lp    = right ? (NT + 1) : 0;
        const float v   = (gl >= 0 && gl < LLEN) ? X[(size_t)(b * NCIN + ci) * LLEN + gl] : 0.0f;
        const int blk   = (ci >> 3) ^ (lp & 7) ^ ((lp >> 3) & 7);
        xt[lp * 64 + blk * 8 + (ci & 7)] = (__bf16)v;
    }
    __syncthreads();

    // ---- W fragments (A-operand): af[tap][ci16], lane holds co=wco*32+l31, ci slice khalf*8 ----
    bf16x8 af[3][4];
    {
        const __bf16* wb = g_Wb + (size_t)b * WPS + (wco * 32 + l31) * 64 + khalf * 8;
        #pragma unroll
        for (int tap = 0; tap < 3; ++tap)
            #pragma unroll
            for (int c16 = 0; c16 < 4; ++c16)
                af[tap][c16] = *(const bf16x8*)(wb + tap * 4096 + c16 * 16);
    }

    // ---- MFMA main: D[32co][32l] tiles, contraction 3 taps x 4 ci16 x K=16 ----
    f32x16 acc[4] = {};
    #pragma unroll
    for (int tap = 0; tap < 3; ++tap) {
        #pragma unroll
        for (int c16 = 0; c16 < 4; ++c16) {
            #pragma unroll
            for (int n = 0; n < 4; ++n) {
                const int R   = wl * 128 + n * 32 + l31 + tap;     // tap-shifted row
                const int blk = (c16 * 2 + khalf) ^ (R & 7) ^ ((R >> 3) & 7);
                bf16x8 bfr = *(const bf16x8*)(xt + R * 64 + blk * 8);
                acc[n] = __builtin_amdgcn_mfma_f32_32x32x16_bf16(af[tap][c16], bfr, acc[n], 0, 0, 0);
            }
        }
    }

    // ---- epilogue: + base_b, LDS transpose (two co-half passes), coalesced stores ----
    #pragma unroll
    for (int m = 0; m < 2; ++m) {
        __syncthreads();   // xt reads (m=0) / ot reads (m=1) complete
        if (wco == m) {
            #pragma unroll
            for (int reg = 0; reg < 16; ++reg) {
                const int row = (reg & 3) + 8 * (reg >> 2) + 4 * khalf;  // co_local 0..31
                const float bb = base_b[m * 32 + row];
                #pragma unroll
                for (int n = 0; n < 4; ++n)
                    ot[row * 258 + wl * 128 + n * 32 + l31] = acc[n][reg] + bb;
            }
        }
        __syncthreads();
        #pragma unroll
        for (int it = 0; it < 8; ++it) {
            const int c   = t + it * 256;            // 0..2047
            const int co2 = c >> 6;                  // staged row 0..31
            const int lr4 = c & 63;                  // f32x4 index in row
            f32x4 v = *(const f32x4*)(ot + co2 * 258 + lr4 * 4);
            const int co = m * 32 + co2;
            *(f32x4*)(out + (size_t)(b * NCOUT + co) * LLEN + l0 + lr4 * 4) = v;
        }
    }
}

// ---------------------------------------------------------------------------
extern "C" void kernel_launch(void* const* d_in, const int* in_sizes, int n_in,
                              void* d_out, int out_size, void* d_ws, size_t ws_size,
                              hipStream_t stream)
{
    const float* X      = (const float*)d_in[0];
    const float* a_emb  = (const float*)d_in[1];
    const float* b_emb  = (const float*)d_in[2];
    const float* A_w1   = (const float*)d_in[3];
    const float* A_b1   = (const float*)d_in[4];
    const float* A_g    = (const float*)d_in[5];
    const float* A_beta = (const float*)d_in[6];
    const float* A_w2   = (const float*)d_in[7];
    const float* A_b2   = (const float*)d_in[8];
    const float* B_w1   = (const float*)d_in[9];
    const float* B_b1   = (const float*)d_in[10];
    const float* B_g    = (const float*)d_in[11];
    const float* B_beta = (const float*)d_in[12];
    const float* B_w2   = (const float*)d_in[13];
    const float* B_b2   = (const float*)d_in[14];
    const float* base_w = (const float*)d_in[15];
    const float* base_b = (const float*)d_in[16];

    float* out = (float*)d_out;   // reference output dtype is float32

    mlp_kernel<<<2 * BS, 256, 0, stream>>>(a_emb, b_emb,
        A_w1, A_b1, A_g, A_beta, A_w2, A_b2,
        B_w1, B_b1, B_g, B_beta, B_w2, B_b2);

    assemble_kernel<<<4 * BS, 256, 0, stream>>>(base_w);

    conv_kernel<<<BS * (LLEN / NT), 256, 0, stream>>>(X, base_b, out);
}